// Round 1
// baseline (95.505 us; speedup 1.0000x reference)
//
#include <hip/hip_runtime.h>

#define N_LC 4194304
#define T_STEPS 20
#define BLOCK 256
#define VEC 4   // float4 per thread

// ---------------------------------------------------------------------------
// Main simulation kernel: each thread owns 4 neurons, keeps (v,u,r) in
// registers across all 20 timesteps, reads one coalesced float4 of noise per
// step, then reduces sum(r) wave->block->global(double atomic).
// ---------------------------------------------------------------------------
__global__ __launch_bounds__(BLOCK) void lc_sim_kernel(
    const float* __restrict__ amygdala,
    const float* __restrict__ insula,
    const float* __restrict__ circadian,
    const float* __restrict__ cms,
    const float* __restrict__ v0,
    const float* __restrict__ u0,
    const float* __restrict__ rate0,
    const float* __restrict__ noise,
    double* __restrict__ ws_sum)
{
    const int idx = blockIdx.x * BLOCK + threadIdx.x;   // float4 index

    // Scalar input-current logic (uniform across threads; broadcast loads)
    const float tonic  = 2.0f + circadian[0] * 3.0f + insula[0] * 5.0f + cms[0] * 3.0f;
    const float phasic = (amygdala[0] > 0.3f) ? 15.0f : 0.0f;
    const float Iconst = tonic + phasic + 0.5f;         // + I_TONIC

    float4 v = reinterpret_cast<const float4*>(v0)[idx];
    float4 u = reinterpret_cast<const float4*>(u0)[idx];
    float4 r = reinterpret_cast<const float4*>(rate0)[idx];

    auto step1 = [&](float& vv, float& uu, float& rr, float n) {
        const float I = Iconst + 0.5f * n;
        vv = vv + (0.04f * vv * vv + 5.0f * vv + 140.0f - uu + I);
        uu = uu + 0.02f * (0.2f * vv - uu);              // uses UPDATED v (matches ref)
        const bool sp = (vv >= 30.0f);
        if (sp) { vv = -65.0f; uu += 8.0f; }
        rr = 0.9f * rr + (sp ? 0.1f : 0.0f);
    };

    #pragma unroll
    for (int t = 0; t < T_STEPS; ++t) {
        const float4 n =
            reinterpret_cast<const float4*>(noise + (size_t)t * N_LC)[idx];
        step1(v.x, u.x, r.x, n.x);
        step1(v.y, u.y, r.y, n.y);
        step1(v.z, u.z, r.z, n.z);
        step1(v.w, u.w, r.w, n.w);
    }

    // ---- reduction of sum(r) ----
    float rsum = (r.x + r.y) + (r.z + r.w);
    #pragma unroll
    for (int off = 32; off > 0; off >>= 1)
        rsum += __shfl_down(rsum, off, 64);

    __shared__ float wave_sum[BLOCK / 64];
    const int lane = threadIdx.x & 63;
    const int wid  = threadIdx.x >> 6;
    if (lane == 0) wave_sum[wid] = rsum;
    __syncthreads();
    if (threadIdx.x == 0) {
        float bsum = 0.0f;
        #pragma unroll
        for (int w = 0; w < BLOCK / 64; ++w) bsum += wave_sum[w];
        atomicAdd(ws_sum, (double)bsum);
    }
}

// ---------------------------------------------------------------------------
// Finalize: scalar noradrenaline readout (float32 op order of the reference).
// ---------------------------------------------------------------------------
__global__ void lc_finalize_kernel(const double* __restrict__ ws_sum,
                                   const float* __restrict__ amygdala,
                                   float* __restrict__ out)
{
    const float lc_mean = (float)(ws_sum[0] / (double)N_LC);
    float raw_na = fminf(fmaxf(lc_mean * 6.0f, 0.0f), 1.0f);
    if (amygdala[0] > 0.3f) raw_na = fminf(raw_na, 0.8f);
    const float na_ema = 0.85f * 0.3f + 0.15f * raw_na;
    const float na = fminf(fmaxf(na_ema, 0.05f), 0.95f);
    out[0] = na;
    out[1] = lc_mean;
    out[2] = fminf(na * 2.0f, 1.0f);
    out[3] = fminf(na * 1.5f, 1.0f);
}

extern "C" void kernel_launch(void* const* d_in, const int* in_sizes, int n_in,
                              void* d_out, int out_size, void* d_ws, size_t ws_size,
                              hipStream_t stream) {
    const float* amygdala  = (const float*)d_in[0];
    const float* insula    = (const float*)d_in[1];
    const float* circadian = (const float*)d_in[2];
    const float* cms       = (const float*)d_in[3];
    const float* v0        = (const float*)d_in[4];
    const float* u0        = (const float*)d_in[5];
    const float* rate0     = (const float*)d_in[6];
    const float* noise     = (const float*)d_in[7];
    float* out             = (float*)d_out;
    double* ws_sum         = (double*)d_ws;

    // ws is poisoned once and never re-poisoned between replays: zero it here.
    hipMemsetAsync(ws_sum, 0, sizeof(double), stream);

    const int grid = N_LC / (BLOCK * VEC);   // 4096 blocks
    lc_sim_kernel<<<grid, BLOCK, 0, stream>>>(
        amygdala, insula, circadian, cms, v0, u0, rate0, noise, ws_sum);

    lc_finalize_kernel<<<1, 1, 0, stream>>>(ws_sum, amygdala, out);
}